// Round 1
// baseline (1291.257 us; speedup 1.0000x reference)
//
#include <hip/hip_runtime.h>
#include <hip/hip_bf16.h>
#include <stdint.h>

// WindowAttention (Swin, shifted): x[2048,49,512] f32 -> out[2048,49,512] f32
// Stages (all bf16 MFMA, f32 accum):
//   ws layout: Wt bf16[1536][512] | Pt bf16[512][512] | qkv bf16[100352][1536] | aout bf16[100352][512]
//   k_wprep: cast+transpose weights
//   k_gemm<1,1>: qkv = x @ qkv_w + qkv_b           (158 GF)
//   k_attn:  per (window,head): softmax(QK^T*s + bias + mask) @ V
//   k_gemm<0,0>: out = aout @ proj_w + proj_b      (53 GF)

#define HEADS 16
#define NTOK  49
#define CH    512

typedef float  f32x4  __attribute__((ext_vector_type(4)));
typedef __bf16 bf16x8 __attribute__((ext_vector_type(8)));
typedef unsigned short u16;
typedef unsigned int   u32;

__device__ __forceinline__ u16 f2bf(float f) {
  u32 u = __builtin_bit_cast(u32, f);
  u32 r = (u + 0x7fffu + ((u >> 16) & 1u)) >> 16;
  return (u16)r;
}

// ---------------- weight prep: Wt[n][k] = bf16(qkv_w[k][n]), Pt likewise ----------------
__global__ __launch_bounds__(256) void k_wprep(const float* __restrict__ qkv_w,
                                               const float* __restrict__ proj_w,
                                               u16* __restrict__ Wt, u16* __restrict__ Pt) {
  int tid = blockIdx.x * 256 + threadIdx.x;
  const int T1 = 1536 * 512;
  if (tid < T1) {
    int n = tid >> 9, k = tid & 511;
    Wt[tid] = f2bf(qkv_w[k * 1536 + n]);
  } else {
    int t2 = tid - T1;   // < 512*512 (grid sized exactly)
    int n = t2 >> 9, k = t2 & 511;
    Pt[t2] = f2bf(proj_w[k * 512 + n]);
  }
}

// ---------------- GEMM: C[M][Nn] = A[M][K] @ Bt[Nn][K]^T + bias ----------------
// 128x128 tile, 4 waves (2x2 of 64x64), BK=32, LDS rows padded to 40 bf16.
template<int A_F32, int OUT_BF16>
__global__ __launch_bounds__(256) void k_gemm(const void* __restrict__ Ap,
                                              const u16* __restrict__ Bt,
                                              const float* __restrict__ bias,
                                              void* __restrict__ Cp,
                                              int M, int Nn, int K, int nbn) {
  __shared__ u16 sA[128 * 40];
  __shared__ u16 sB[128 * 40];
  const int t    = threadIdx.x;
  const int bid  = blockIdx.x;
  const int cb   = bid % nbn, rb = bid / nbn;   // consecutive bids share rb -> A-tile L2/L3 reuse
  const int row0 = rb << 7, col0 = cb << 7;
  const int lane = t & 63, w = t >> 6;
  const int wr = (w >> 1) * 64, wc = (w & 1) * 64;
  const int lm = lane & 15, lk = lane >> 4;

  const f32x4 fz = {0.f, 0.f, 0.f, 0.f};
  f32x4 acc[4][4];
#pragma unroll
  for (int i = 0; i < 4; i++)
#pragma unroll
    for (int j = 0; j < 4; j++) acc[i][j] = fz;

  float4 fA[4];
  int4   iA[2], iB[2];
  const int nk = K >> 5;

  auto g_load = [&](int kt) {
    const int kb = kt << 5;
    if (A_F32) {
      const float* A = (const float*)Ap;
#pragma unroll
      for (int i = 0; i < 4; i++) {
        int q = t + (i << 8);
        int r = q >> 3, c = (q & 7) << 2;
        fA[i] = *(const float4*)(A + (size_t)(row0 + r) * K + kb + c);
      }
    } else {
      const u16* A = (const u16*)Ap;
#pragma unroll
      for (int i = 0; i < 2; i++) {
        int q = t + (i << 8);
        int r = q >> 2, c = (q & 3) << 3;
        iA[i] = *(const int4*)(A + (size_t)(row0 + r) * K + kb + c);
      }
    }
#pragma unroll
    for (int i = 0; i < 2; i++) {
      int q = t + (i << 8);
      int r = q >> 2, c = (q & 3) << 3;
      iB[i] = *(const int4*)(Bt + (size_t)(col0 + r) * K + kb + c);
    }
  };

  auto s_store = [&]() {
    if (A_F32) {
#pragma unroll
      for (int i = 0; i < 4; i++) {
        int q = t + (i << 8);
        int r = q >> 3, c = (q & 7) << 2;
        u32 w0 = (u32)f2bf(fA[i].x) | ((u32)f2bf(fA[i].y) << 16);
        u32 w1 = (u32)f2bf(fA[i].z) | ((u32)f2bf(fA[i].w) << 16);
        u32* d = (u32*)(sA + r * 40 + c);
        d[0] = w0; d[1] = w1;
      }
    } else {
#pragma unroll
      for (int i = 0; i < 2; i++) {
        int q = t + (i << 8);
        int r = q >> 2, c = (q & 3) << 3;
        *(int4*)(sA + r * 40 + c) = iA[i];
      }
    }
#pragma unroll
    for (int i = 0; i < 2; i++) {
      int q = t + (i << 8);
      int r = q >> 2, c = (q & 3) << 3;
      *(int4*)(sB + r * 40 + c) = iB[i];
    }
  };

  g_load(0);
  for (int kt = 0; kt < nk; kt++) {
    __syncthreads();
    s_store();
    __syncthreads();
    if (kt + 1 < nk) g_load(kt + 1);   // overlap next-tile global loads with MFMA
    bf16x8 a[4], b[4];
#pragma unroll
    for (int mi = 0; mi < 4; mi++)
      a[mi] = *(const bf16x8*)(sA + (wr + mi * 16 + lm) * 40 + lk * 8);
#pragma unroll
    for (int ni = 0; ni < 4; ni++)
      b[ni] = *(const bf16x8*)(sB + (wc + ni * 16 + lm) * 40 + lk * 8);
#pragma unroll
    for (int mi = 0; mi < 4; mi++)
#pragma unroll
      for (int ni = 0; ni < 4; ni++)
        acc[mi][ni] = __builtin_amdgcn_mfma_f32_16x16x32_bf16(a[mi], b[ni], acc[mi][ni], 0, 0, 0);
  }

#pragma unroll
  for (int mi = 0; mi < 4; mi++) {
#pragma unroll
    for (int ni = 0; ni < 4; ni++) {
      int col = col0 + wc + ni * 16 + lm;
      float bv = bias[col];
#pragma unroll
      for (int r = 0; r < 4; r++) {
        int row = row0 + wr + mi * 16 + lk * 4 + r;
        float v = acc[mi][ni][r] + bv;
        if (OUT_BF16) ((u16*)Cp)[(size_t)row * Nn + col] = f2bf(v);
        else          ((float*)Cp)[(size_t)row * Nn + col] = v;
      }
    }
  }
}

// ---------------- fused window attention: one wave per (window, head) ----------------
__global__ __launch_bounds__(64) void k_attn(const u16* __restrict__ qkv,
                                             const float* __restrict__ bias_table,
                                             u16* __restrict__ aout) {
  __shared__ u16 sP[64 * 72];
  __shared__ u16 sV[32 * 72];
  const int bid = blockIdx.x;
  const int wdx = bid >> 4;       // window 0..2047
  const int h   = bid & 15;
  const int mw  = wdx & 63;       // mask/window index within the 8x8 grid
  const int l   = threadIdx.x;
  const int lm  = l & 15, lk = l >> 4;
  const size_t tb = (size_t)wdx * NTOK;
  const u16* base = qkv + tb * 1536;

  const int4  iz = make_int4(0, 0, 0, 0);
  const f32x4 fz = {0.f, 0.f, 0.f, 0.f};

  // stage V transposed: sV[d][n] = V[n][d]; pad n>=49 with zeros
  {
    const int n = l;
    const u16* vp = base + (size_t)n * 1536 + 1024 + h * 32;
#pragma unroll
    for (int d0 = 0; d0 < 4; d0++) {
      int4 vv = (n < NTOK) ? *(const int4*)(vp + d0 * 8) : iz;
      const u16* u = (const u16*)&vv;
#pragma unroll
      for (int j = 0; j < 8; j++) sV[(d0 * 8 + j) * 72 + n] = u[j];
    }
  }

  // Q,K fragments straight from global (pad rows >= 49 with zeros)
  bf16x8 qf[4], kf[4];
#pragma unroll
  for (int i = 0; i < 4; i++) {
    int m = i * 16 + lm;
    int4 qi = (m < NTOK) ? *(const int4*)(base + (size_t)m * 1536 +       h * 32 + lk * 8) : iz;
    int4 ki = (m < NTOK) ? *(const int4*)(base + (size_t)m * 1536 + 512 + h * 32 + lk * 8) : iz;
    qf[i] = __builtin_bit_cast(bf16x8, qi);
    kf[i] = __builtin_bit_cast(bf16x8, ki);
  }

  f32x4 s[4][4];
#pragma unroll
  for (int mi = 0; mi < 4; mi++)
#pragma unroll
    for (int ni = 0; ni < 4; ni++)
      s[mi][ni] = __builtin_amdgcn_mfma_f32_16x16x32_bf16(qf[mi], kf[ni], fz, 0, 0, 0);

  const float scale = 0.17677669529663687f;   // 32^-0.5
  const int mwR = (mw >> 3) * 7, mwC = (mw & 7) * 7;
  float rinv[4][4];

#pragma unroll
  for (int mi = 0; mi < 4; mi++) {
    float rmax[4] = {-1e30f, -1e30f, -1e30f, -1e30f};
#pragma unroll
    for (int ni = 0; ni < 4; ni++) {
      int col = ni * 16 + lm;
#pragma unroll
      for (int r = 0; r < 4; r++) {
        int row = mi * 16 + lk * 4 + r;
        float v = -1e30f;
        if (row < NTOK && col < NTOK) {
          int ih = row / 7, iw = row - ih * 7;
          int jh = col / 7, jw = col - jh * 7;
          float b = bias_table[((ih - jh + 6) * 13 + (iw - jw + 6)) * HEADS + h];
          int gih = mwR + ih, giw = mwC + iw, gjh = mwR + jh, gjw = mwC + jw;
          int ri = (gih < 49 ? 0 : (gih < 53 ? 1 : 2)) * 3 + (giw < 49 ? 0 : (giw < 53 ? 1 : 2));
          int rj = (gjh < 49 ? 0 : (gjh < 53 ? 1 : 2)) * 3 + (gjw < 49 ? 0 : (gjw < 53 ? 1 : 2));
          v = s[mi][ni][r] * scale + b + ((ri != rj) ? -100.f : 0.f);
        }
        s[mi][ni][r] = v;
        rmax[r] = fmaxf(rmax[r], v);
      }
    }
#pragma unroll
    for (int r = 0; r < 4; r++) {
      float m = rmax[r];
#pragma unroll
      for (int d = 1; d < 16; d <<= 1) m = fmaxf(m, __shfl_xor(m, d, 64));
      rmax[r] = m;
    }
    float rsum[4] = {0.f, 0.f, 0.f, 0.f};
#pragma unroll
    for (int ni = 0; ni < 4; ni++) {
#pragma unroll
      for (int r = 0; r < 4; r++) {
        float p = __expf(s[mi][ni][r] - rmax[r]);   // masked cols -> exp(-huge) = 0
        s[mi][ni][r] = p;
        rsum[r] += p;
      }
    }
#pragma unroll
    for (int r = 0; r < 4; r++) {
      float sm = rsum[r];
#pragma unroll
      for (int d = 1; d < 16; d <<= 1) sm += __shfl_xor(sm, d, 64);
      rinv[mi][r] = 1.f / sm;
    }
#pragma unroll
    for (int ni = 0; ni < 4; ni++)
#pragma unroll
      for (int r = 0; r < 4; r++)
        sP[(mi * 16 + lk * 4 + r) * 72 + ni * 16 + lm] = f2bf(s[mi][ni][r]);
  }

  __syncthreads();

  // O = P @ V  (unnormalized P; rescale by 1/rowsum at the end)
  f32x4 o[4][2];
#pragma unroll
  for (int mi = 0; mi < 4; mi++) { o[mi][0] = fz; o[mi][1] = fz; }
#pragma unroll
  for (int kt = 0; kt < 2; kt++) {
    bf16x8 vb[2];
#pragma unroll
    for (int df = 0; df < 2; df++)
      vb[df] = *(const bf16x8*)(sV + (df * 16 + lm) * 72 + kt * 32 + lk * 8);
#pragma unroll
    for (int mi = 0; mi < 4; mi++) {
      bf16x8 pa = *(const bf16x8*)(sP + (mi * 16 + lm) * 72 + kt * 32 + lk * 8);
      o[mi][0] = __builtin_amdgcn_mfma_f32_16x16x32_bf16(pa, vb[0], o[mi][0], 0, 0, 0);
      o[mi][1] = __builtin_amdgcn_mfma_f32_16x16x32_bf16(pa, vb[1], o[mi][1], 0, 0, 0);
    }
  }

#pragma unroll
  for (int mi = 0; mi < 4; mi++) {
#pragma unroll
    for (int r = 0; r < 4; r++) {
      int row = mi * 16 + lk * 4 + r;
      if (row < NTOK) {
        float inv = rinv[mi][r];
        size_t ob = (tb + row) * CH + h * 32;
        aout[ob + lm]      = f2bf(o[mi][0][r] * inv);
        aout[ob + 16 + lm] = f2bf(o[mi][1][r] * inv);
      }
    }
  }
}

extern "C" void kernel_launch(void* const* d_in, const int* in_sizes, int n_in,
                              void* d_out, int out_size, void* d_ws, size_t ws_size,
                              hipStream_t stream) {
  const float* x      = (const float*)d_in[0];
  const float* qkv_w  = (const float*)d_in[1];
  const float* qkv_b  = (const float*)d_in[2];
  const float* proj_w = (const float*)d_in[3];
  const float* proj_b = (const float*)d_in[4];
  const float* btab   = (const float*)d_in[5];

  char* ws  = (char*)d_ws;
  u16* Wt   = (u16*)ws;                                   // 1536*512*2      = 1,572,864 B
  u16* Pt   = (u16*)(ws + 1572864);                       // 512*512*2       =   524,288 B
  u16* qkv  = (u16*)(ws + 2097152);                       // 100352*1536*2   = 308,281,344 B
  u16* aout = (u16*)(ws + 2097152 + 308281344ull);        // 100352*512*2    = 102,760,448 B
  float* out = (float*)d_out;

  k_wprep<<<4096, 256, 0, stream>>>(qkv_w, proj_w, Wt, Pt);
  k_gemm<1, 1><<<784 * 12, 256, 0, stream>>>((const void*)x, Wt, qkv_b, (void*)qkv,
                                             100352, 1536, 512, 12);
  k_attn<<<2048 * 16, 64, 0, stream>>>(qkv, btab, aout);
  k_gemm<0, 0><<<784 * 4, 256, 0, stream>>>((const void*)aout, Pt, proj_b, (void*)out,
                                            100352, 512, 512, 4);
}

// Round 2
// 940.178 us; speedup vs baseline: 1.3734x; 1.3734x over previous
//
#include <hip/hip_runtime.h>
#include <hip/hip_bf16.h>
#include <stdint.h>

// WindowAttention (Swin, shifted): x[2048,49,512] f32 -> out[2048,49,512] f32
// Pipeline:
//   k_wprep: cast+transpose weights to bf16 [N][K]
//   k_xcast: x f32 -> bf16 (into aout region, dead until attn writes it)
//   k_tabs : bias[h][64][64], mask[mw][64][64] f32 tables (pad rows/cols = -1e30)
//   k_gemm<0>: qkv = xb @ Wt^T + qkv_b     (bf16 out, 158 GF)
//   k_attn : per (window,head) wave: softmax(QK^T*s + bias + mask) @ V
//   k_gemm<1>: out = aout @ Pt^T + proj_b  (f32 out, 53 GF)

#define HEADS 16
#define NTOK  49
#define CH    512

typedef float  f32x4  __attribute__((ext_vector_type(4)));
typedef __bf16 bf16x8 __attribute__((ext_vector_type(8)));
typedef unsigned short u16;
typedef unsigned int   u32;

__device__ __forceinline__ u16 f2bf(float f) {
  u32 u = __builtin_bit_cast(u32, f);
  u32 r = (u + 0x7fffu + ((u >> 16) & 1u)) >> 16;
  return (u16)r;
}

__device__ __forceinline__ void gload16(const u16* g, u16* l) {
  __builtin_amdgcn_global_load_lds(
      (const __attribute__((address_space(1))) u32*)g,
      (__attribute__((address_space(3))) u32*)l, 16, 0, 0);
}

// ---------------- weight prep ----------------
__global__ __launch_bounds__(256) void k_wprep(const float* __restrict__ qkv_w,
                                               const float* __restrict__ proj_w,
                                               u16* __restrict__ Wt, u16* __restrict__ Pt) {
  int tid = blockIdx.x * 256 + threadIdx.x;
  const int T1 = 1536 * 512;
  if (tid < T1) {
    int n = tid >> 9, k = tid & 511;
    Wt[tid] = f2bf(qkv_w[k * 1536 + n]);
  } else {
    int t2 = tid - T1;
    int n = t2 >> 9, k = t2 & 511;
    Pt[t2] = f2bf(proj_w[k * 512 + n]);
  }
}

// ---------------- x cast: f32 -> bf16, 8 elems/thread ----------------
__global__ __launch_bounds__(256) void k_xcast(const float* __restrict__ x,
                                               u16* __restrict__ xb) {
  int tid = blockIdx.x * 256 + threadIdx.x;
  const float4* xv = (const float4*)x;
  float4 a = xv[tid * 2], b = xv[tid * 2 + 1];
  u16 o[8] = {f2bf(a.x), f2bf(a.y), f2bf(a.z), f2bf(a.w),
              f2bf(b.x), f2bf(b.y), f2bf(b.z), f2bf(b.w)};
  ((int4*)xb)[tid] = *(const int4*)o;
}

// ---------------- bias/mask tables ----------------
__global__ __launch_bounds__(256) void k_tabs(const float* __restrict__ bias_table,
                                              float* __restrict__ biasM,
                                              float* __restrict__ maskT) {
  int tid = blockIdx.x * 256 + threadIdx.x;
  if (tid < 16 * 4096) {
    int h = tid >> 12, rc = tid & 4095, r = rc >> 6, c = rc & 63;
    float v = -1e30f;
    if (r < NTOK && c < NTOK) {
      int ih = r / 7, iw = r - ih * 7, jh = c / 7, jw = c - jh * 7;
      v = bias_table[((ih - jh + 6) * 13 + (iw - jw + 6)) * HEADS + h];
    }
    biasM[tid] = v;
  } else {
    int t2 = tid - 65536;
    int mw = t2 >> 12, rc = t2 & 4095, r = rc >> 6, c = rc & 63;
    float v = 0.f;
    if (r < NTOK && c < NTOK) {
      int mwR = (mw >> 3) * 7, mwC = (mw & 7) * 7;
      int ih = r / 7, iw = r - ih * 7, jh = c / 7, jw = c - jh * 7;
      int gih = mwR + ih, giw = mwC + iw, gjh = mwR + jh, gjw = mwC + jw;
      int ri = (gih < 49 ? 0 : (gih < 53 ? 1 : 2)) * 3 + (giw < 49 ? 0 : (giw < 53 ? 1 : 2));
      int rj = (gjh < 49 ? 0 : (gjh < 53 ? 1 : 2)) * 3 + (gjw < 49 ? 0 : (gjw < 53 ? 1 : 2));
      v = (ri != rj) ? -100.f : 0.f;
    }
    maskT[t2] = v;
  }
}

// ---------------- GEMM: C[M][Nn] = A[M][K] @ Bt[Nn][K]^T + bias ----------------
// 128x128 tile, 4 waves (2x2 of 64x64), BK=64, global_load_lds(16B) staging,
// LDS-staged coalesced epilogue.
template<int OUT_F32>
__global__ __launch_bounds__(256) void k_gemm(const u16* __restrict__ A,
                                              const u16* __restrict__ Bt,
                                              const float* __restrict__ bias,
                                              void* __restrict__ Cp,
                                              int M, int Nn, int K, int nbn) {
  __shared__ u16 smem[128 * 136];            // 34816 B; loop uses first 32 KB
  u16* sA = smem;                            // [128][64] linear (gload_lds)
  u16* sB = smem + 8192;
  const int t   = threadIdx.x;
  const int bid = blockIdx.x;
  const int cb  = bid % nbn, rb = bid / nbn; // consecutive bids share rb
  const int row0 = rb << 7, col0 = cb << 7;
  const int lane = t & 63, w = t >> 6;
  const int wr = (w >> 1) << 6, wc = (w & 1) << 6;
  const int lm = lane & 15, lk = lane >> 4;

  const f32x4 fz = {0.f, 0.f, 0.f, 0.f};
  f32x4 acc[4][4];
#pragma unroll
  for (int i = 0; i < 4; i++)
#pragma unroll
    for (int j = 0; j < 4; j++) acc[i][j] = fz;

  const int nk = K >> 6;
  for (int kt = 0; kt < nk; ++kt) {
    const int kb = kt << 6;
    __syncthreads();                         // protect LDS from prev readers
#pragma unroll
    for (int i = 0; i < 4; ++i) {
      int q = (i << 8) + t;
      int r = q >> 3, c = (q & 7) << 3;
      int db = ((i << 8) + (t & 192)) << 3;  // wave-uniform dest base (u16 elems)
      gload16(A  + (size_t)(row0 + r) * K + kb + c, sA + db);
      gload16(Bt + (size_t)(col0 + r) * K + kb + c, sB + db);
    }
    __syncthreads();                         // drains vmcnt -> LDS ready
    bf16x8 a[4][2], b[4][2];
#pragma unroll
    for (int mi = 0; mi < 4; ++mi) {
      const u16* p = sA + (wr + mi * 16 + lm) * 64 + lk * 8;
      a[mi][0] = *(const bf16x8*)p;
      a[mi][1] = *(const bf16x8*)(p + 32);
    }
#pragma unroll
    for (int ni = 0; ni < 4; ++ni) {
      const u16* p = sB + (wc + ni * 16 + lm) * 64 + lk * 8;
      b[ni][0] = *(const bf16x8*)p;
      b[ni][1] = *(const bf16x8*)(p + 32);
    }
#pragma unroll
    for (int kk = 0; kk < 2; ++kk)
#pragma unroll
      for (int mi = 0; mi < 4; ++mi)
#pragma unroll
        for (int ni = 0; ni < 4; ++ni)
          acc[mi][ni] = __builtin_amdgcn_mfma_f32_16x16x32_bf16(a[mi][kk], b[ni][kk],
                                                                acc[mi][ni], 0, 0, 0);
  }

  if constexpr (!OUT_F32) {
    // bf16 out: stage whole 128x128 tile in LDS (stride 136), coalesced copy
    __syncthreads();
#pragma unroll
    for (int mi = 0; mi < 4; ++mi)
#pragma unroll
      for (int ni = 0; ni < 4; ++ni) {
        int col = wc + ni * 16 + lm;
        float bv = bias[col0 + col];
#pragma unroll
        for (int r = 0; r < 4; ++r)
          smem[(wr + mi * 16 + lk * 4 + r) * 136 + col] = f2bf(acc[mi][ni][r] + bv);
      }
    __syncthreads();
    const int rr = t >> 1, seg = t & 1;
    u16* dst = (u16*)Cp + (size_t)(row0 + rr) * Nn + col0 + seg * 64;
    const u16* src = smem + rr * 136 + seg * 64;
#pragma unroll
    for (int i = 0; i < 8; ++i)
      *(int4*)(dst + i * 8) = *(const int4*)(src + i * 8);
  } else {
    // f32 out: two half-tiles of 64x128 f32 (stride 132) through LDS
    float* smf = (float*)smem;
    for (int half = 0; half < 2; ++half) {
      __syncthreads();
      if ((w >> 1) == half) {
#pragma unroll
        for (int mi = 0; mi < 4; ++mi)
#pragma unroll
          for (int ni = 0; ni < 4; ++ni) {
            int col = wc + ni * 16 + lm;
            float bv = bias[col0 + col];
#pragma unroll
            for (int r = 0; r < 4; ++r)
              smf[(mi * 16 + lk * 4 + r) * 132 + col] = acc[mi][ni][r] + bv;
          }
      }
      __syncthreads();
      const int rr = t >> 2, seg = t & 3;
      float* dst = (float*)Cp + (size_t)(row0 + half * 64 + rr) * Nn + col0 + seg * 32;
      const float* src = smf + rr * 132 + seg * 32;
#pragma unroll
      for (int i = 0; i < 8; ++i)
        *(float4*)(dst + i * 4) = *(const float4*)(src + i * 4);
    }
  }
}

// ---------------- fused window attention: one wave per (window, head) ----------------
__global__ __launch_bounds__(64) void k_attn(const u16* __restrict__ qkv,
                                             const float* __restrict__ biasM,
                                             const float* __restrict__ maskT,
                                             u16* __restrict__ aout) {
  __shared__ u16 sP[64 * 72];
  __shared__ u16 sV[32 * 72];
  const int bid = blockIdx.x;
  const int wdx = bid >> 4;       // window 0..2047
  const int h   = bid & 15;
  const int mw  = wdx & 63;
  const int l   = threadIdx.x;
  const int lm  = l & 15, lk = l >> 4;
  const size_t tb = (size_t)wdx * NTOK;
  const u16* base = qkv + tb * 1536;

  const int4  iz = make_int4(0, 0, 0, 0);
  const f32x4 fz = {0.f, 0.f, 0.f, 0.f};

  // stage V transposed: sV[d][n] = V[n][d]
  {
    const int n = l;
    const u16* vp = base + (size_t)n * 1536 + 1024 + h * 32;
#pragma unroll
    for (int d0 = 0; d0 < 4; d0++) {
      int4 vv = (n < NTOK) ? *(const int4*)(vp + d0 * 8) : iz;
      const u16* u = (const u16*)&vv;
#pragma unroll
      for (int j = 0; j < 8; j++) sV[(d0 * 8 + j) * 72 + n] = u[j];
    }
  }

  bf16x8 qf[4], kf[4];
#pragma unroll
  for (int i = 0; i < 4; i++) {
    int m = i * 16 + lm;
    int4 qi = (m < NTOK) ? *(const int4*)(base + (size_t)m * 1536 +       h * 32 + lk * 8) : iz;
    int4 ki = (m < NTOK) ? *(const int4*)(base + (size_t)m * 1536 + 512 + h * 32 + lk * 8) : iz;
    qf[i] = __builtin_bit_cast(bf16x8, qi);
    kf[i] = __builtin_bit_cast(bf16x8, ki);
  }

  f32x4 s[4][4];
#pragma unroll
  for (int mi = 0; mi < 4; mi++)
#pragma unroll
    for (int ni = 0; ni < 4; ni++)
      s[mi][ni] = __builtin_amdgcn_mfma_f32_16x16x32_bf16(qf[mi], kf[ni], fz, 0, 0, 0);

  const float scale = 0.17677669529663687f;   // 32^-0.5
  const float* bM = biasM + (h << 12);
  const float* mT = maskT + (mw << 12);
  float rinv[4][4];

#pragma unroll
  for (int mi = 0; mi < 4; mi++) {
    float rmax[4] = {-3e38f, -3e38f, -3e38f, -3e38f};
#pragma unroll
    for (int ni = 0; ni < 4; ni++) {
#pragma unroll
      for (int r = 0; r < 4; r++) {
        int off = mi * 1024 + lk * 256 + r * 64 + ni * 16 + lm;
        float v = s[mi][ni][r] * scale + bM[off] + mT[off];
        s[mi][ni][r] = v;
        rmax[r] = fmaxf(rmax[r], v);
      }
    }
#pragma unroll
    for (int r = 0; r < 4; r++) {
      float m = rmax[r];
#pragma unroll
      for (int d = 1; d < 16; d <<= 1) m = fmaxf(m, __shfl_xor(m, d, 64));
      rmax[r] = m;
    }
    float rsum[4] = {0.f, 0.f, 0.f, 0.f};
#pragma unroll
    for (int ni = 0; ni < 4; ni++) {
#pragma unroll
      for (int r = 0; r < 4; r++) {
        float p = __expf(s[mi][ni][r] - rmax[r]);
        s[mi][ni][r] = p;
        rsum[r] += p;
      }
    }
#pragma unroll
    for (int r = 0; r < 4; r++) {
      float sm = rsum[r];
#pragma unroll
      for (int d = 1; d < 16; d <<= 1) sm += __shfl_xor(sm, d, 64);
      rinv[mi][r] = 1.f / sm;
    }
#pragma unroll
    for (int ni = 0; ni < 4; ni++)
#pragma unroll
      for (int r = 0; r < 4; r++)
        sP[(mi * 16 + lk * 4 + r) * 72 + ni * 16 + lm] = f2bf(s[mi][ni][r]);
  }

  __syncthreads();

  f32x4 o[4][2];
#pragma unroll
  for (int mi = 0; mi < 4; mi++) { o[mi][0] = fz; o[mi][1] = fz; }
#pragma unroll
  for (int kt = 0; kt < 2; kt++) {
    bf16x8 vb[2];
#pragma unroll
    for (int df = 0; df < 2; df++)
      vb[df] = *(const bf16x8*)(sV + (df * 16 + lm) * 72 + kt * 32 + lk * 8);
#pragma unroll
    for (int mi = 0; mi < 4; mi++) {
      bf16x8 pa = *(const bf16x8*)(sP + (mi * 16 + lm) * 72 + kt * 32 + lk * 8);
      o[mi][0] = __builtin_amdgcn_mfma_f32_16x16x32_bf16(pa, vb[0], o[mi][0], 0, 0, 0);
      o[mi][1] = __builtin_amdgcn_mfma_f32_16x16x32_bf16(pa, vb[1], o[mi][1], 0, 0, 0);
    }
  }

#pragma unroll
  for (int mi = 0; mi < 4; mi++) {
#pragma unroll
    for (int r = 0; r < 4; r++) {
      int row = mi * 16 + lk * 4 + r;
      if (row < NTOK) {
        float inv = rinv[mi][r];
        size_t ob = (tb + row) * CH + h * 32;
        aout[ob + lm]      = f2bf(o[mi][0][r] * inv);
        aout[ob + 16 + lm] = f2bf(o[mi][1][r] * inv);
      }
    }
  }
}

extern "C" void kernel_launch(void* const* d_in, const int* in_sizes, int n_in,
                              void* d_out, int out_size, void* d_ws, size_t ws_size,
                              hipStream_t stream) {
  const float* x      = (const float*)d_in[0];
  const float* qkv_b  = (const float*)d_in[2];
  const float* proj_b = (const float*)d_in[4];
  const float* btab   = (const float*)d_in[5];

  char* ws   = (char*)d_ws;
  u16* Wt    = (u16*)ws;                                  // 1,572,864 B
  u16* Pt    = (u16*)(ws + 1572864);                      //   524,288 B
  u16* qkv   = (u16*)(ws + 2097152);                      // 308,281,344 B
  u16* aout  = (u16*)(ws + 2097152 + 308281344ull);       // 102,760,448 B (aliased xb)
  u16* xb    = aout;                                      // dead once attn writes aout
  float* biasM = (float*)(ws + 2097152 + 308281344ull + 102760448ull);  // 262,144 B
  float* maskT = biasM + 65536;                           // 1,048,576 B
  float* out = (float*)d_out;

  k_wprep<<<4096, 256, 0, stream>>>((const float*)d_in[1], (const float*)d_in[3], Wt, Pt);
  k_xcast<<<25088, 256, 0, stream>>>(x, xb);
  k_tabs<<<1280, 256, 0, stream>>>(btab, biasM, maskT);
  k_gemm<0><<<784 * 12, 256, 0, stream>>>(xb, Wt, qkv_b, (void*)qkv, 100352, 1536, 512, 12);
  k_attn<<<2048 * 16, 64, 0, stream>>>(qkv, biasM, maskT, aout);
  k_gemm<1><<<784 * 4, 256, 0, stream>>>(aout, Pt, proj_b, (void*)out, 100352, 512, 512, 4);
}

// Round 3
// 825.800 us; speedup vs baseline: 1.5636x; 1.1385x over previous
//
#include <hip/hip_runtime.h>
#include <hip/hip_bf16.h>
#include <stdint.h>

// WindowAttention (Swin, shifted): x[2048,49,512] f32 -> out[2048,49,512] f32
// Pipeline:
//   k_wprep: cast+transpose weights to bf16 [N][K]; q-cols pre-scaled by 32^-0.5; bias2
//   k_xcast: x f32 -> bf16 (into aout region, dead until attn writes it)
//   k_tabs : bias[h][64][64], mask[mw][64][64] f32 tables (pad rows/cols = -1e30)
//   k_gemm<0>: qkv = xb @ Wt^T + bias2     (bf16 out, 158 GF)
//   k_attn : 4-wave blocks, wave=(window,head): softmax(QK^T + bias + mask) @ V
//   k_gemm<1>: out = aout @ Pt^T + proj_b  (f32 out, 53 GF)

#define HEADS 16
#define NTOK  49
#define CH    512

typedef float  f32x4  __attribute__((ext_vector_type(4)));
typedef __bf16 bf16x8 __attribute__((ext_vector_type(8)));
typedef unsigned short u16;
typedef unsigned int   u32;

__device__ __forceinline__ u16 f2bf(float f) {
  return __builtin_bit_cast(u16, (__bf16)f);   // native v_cvt, RNE
}

__device__ __forceinline__ void gload16(const u16* g, u16* l) {
  __builtin_amdgcn_global_load_lds(
      (const __attribute__((address_space(1))) u32*)g,
      (__attribute__((address_space(3))) u32*)l, 16, 0, 0);
}

// ---------------- weight prep (+ q-scale folding) ----------------
__global__ __launch_bounds__(256) void k_wprep(const float* __restrict__ qkv_w,
                                               const float* __restrict__ proj_w,
                                               const float* __restrict__ qkv_b,
                                               u16* __restrict__ Wt, u16* __restrict__ Pt,
                                               float* __restrict__ bias2) {
  const float sc = 0.17677669529663687f;       // 32^-0.5
  int tid = blockIdx.x * 256 + threadIdx.x;
  const int T1 = 1536 * 512;
  if (tid < 1536) bias2[tid] = qkv_b[tid] * (tid < 512 ? sc : 1.f);
  if (tid < T1) {
    int n = tid >> 9, k = tid & 511;
    float v = qkv_w[k * 1536 + n];
    if (n < 512) v *= sc;
    Wt[tid] = f2bf(v);
  } else {
    int t2 = tid - T1;
    int n = t2 >> 9, k = t2 & 511;
    Pt[t2] = f2bf(proj_w[k * 512 + n]);
  }
}

// ---------------- x cast: f32 -> bf16, 8 elems/thread ----------------
__global__ __launch_bounds__(256) void k_xcast(const float* __restrict__ x,
                                               u16* __restrict__ xb) {
  int tid = blockIdx.x * 256 + threadIdx.x;
  const float4* xv = (const float4*)x;
  float4 a = xv[tid * 2], b = xv[tid * 2 + 1];
  u16 o[8] = {f2bf(a.x), f2bf(a.y), f2bf(a.z), f2bf(a.w),
              f2bf(b.x), f2bf(b.y), f2bf(b.z), f2bf(b.w)};
  ((int4*)xb)[tid] = *(const int4*)o;
}

// ---------------- bias/mask tables ----------------
__global__ __launch_bounds__(256) void k_tabs(const float* __restrict__ bias_table,
                                              float* __restrict__ biasM,
                                              float* __restrict__ maskT) {
  int tid = blockIdx.x * 256 + threadIdx.x;
  if (tid < 16 * 4096) {
    int h = tid >> 12, rc = tid & 4095, r = rc >> 6, c = rc & 63;
    float v = -1e30f;
    if (r < NTOK && c < NTOK) {
      int ih = r / 7, iw = r - ih * 7, jh = c / 7, jw = c - jh * 7;
      v = bias_table[((ih - jh + 6) * 13 + (iw - jw + 6)) * HEADS + h];
    }
    biasM[tid] = v;
  } else {
    int t2 = tid - 65536;
    int mw = t2 >> 12, rc = t2 & 4095, r = rc >> 6, c = rc & 63;
    float v = 0.f;
    if (r < NTOK && c < NTOK) {
      int mwR = (mw >> 3) * 7, mwC = (mw & 7) * 7;
      int ih = r / 7, iw = r - ih * 7, jh = c / 7, jw = c - jh * 7;
      int gih = mwR + ih, giw = mwC + iw, gjh = mwR + jh, gjw = mwC + jw;
      int ri = (gih < 49 ? 0 : (gih < 53 ? 1 : 2)) * 3 + (giw < 49 ? 0 : (giw < 53 ? 1 : 2));
      int rj = (gjh < 49 ? 0 : (gjh < 53 ? 1 : 2)) * 3 + (gjw < 49 ? 0 : (gjw < 53 ? 1 : 2));
      v = (ri != rj) ? -100.f : 0.f;
    }
    maskT[t2] = v;
  }
}

// ---------------- GEMM: C[M][Nn] = A[M][K] @ Bt[Nn][K]^T + bias ----------------
template<int OUT_F32>
__global__ __launch_bounds__(256) void k_gemm(const u16* __restrict__ A,
                                              const u16* __restrict__ Bt,
                                              const float* __restrict__ bias,
                                              void* __restrict__ Cp,
                                              int M, int Nn, int K, int nbn) {
  __shared__ u16 smem[128 * 136];
  u16* sA = smem;
  u16* sB = smem + 8192;
  const int t   = threadIdx.x;
  const int bid = blockIdx.x;
  const int cb  = bid % nbn, rb = bid / nbn;
  const int row0 = rb << 7, col0 = cb << 7;
  const int lane = t & 63, w = t >> 6;
  const int wr = (w >> 1) << 6, wc = (w & 1) << 6;
  const int lm = lane & 15, lk = lane >> 4;

  const f32x4 fz = {0.f, 0.f, 0.f, 0.f};
  f32x4 acc[4][4];
#pragma unroll
  for (int i = 0; i < 4; i++)
#pragma unroll
    for (int j = 0; j < 4; j++) acc[i][j] = fz;

  const int nk = K >> 6;
  for (int kt = 0; kt < nk; ++kt) {
    const int kb = kt << 6;
    __syncthreads();
#pragma unroll
    for (int i = 0; i < 4; ++i) {
      int q = (i << 8) + t;
      int r = q >> 3, c = (q & 7) << 3;
      int db = ((i << 8) + (t & 192)) << 3;
      gload16(A  + (size_t)(row0 + r) * K + kb + c, sA + db);
      gload16(Bt + (size_t)(col0 + r) * K + kb + c, sB + db);
    }
    __syncthreads();
    bf16x8 a[4][2], b[4][2];
#pragma unroll
    for (int mi = 0; mi < 4; ++mi) {
      const u16* p = sA + (wr + mi * 16 + lm) * 64 + lk * 8;
      a[mi][0] = *(const bf16x8*)p;
      a[mi][1] = *(const bf16x8*)(p + 32);
    }
#pragma unroll
    for (int ni = 0; ni < 4; ++ni) {
      const u16* p = sB + (wc + ni * 16 + lm) * 64 + lk * 8;
      b[ni][0] = *(const bf16x8*)p;
      b[ni][1] = *(const bf16x8*)(p + 32);
    }
#pragma unroll
    for (int kk = 0; kk < 2; ++kk)
#pragma unroll
      for (int mi = 0; mi < 4; ++mi)
#pragma unroll
        for (int ni = 0; ni < 4; ++ni)
          acc[mi][ni] = __builtin_amdgcn_mfma_f32_16x16x32_bf16(a[mi][kk], b[ni][kk],
                                                                acc[mi][ni], 0, 0, 0);
  }

  if constexpr (!OUT_F32) {
    __syncthreads();
#pragma unroll
    for (int mi = 0; mi < 4; ++mi)
#pragma unroll
      for (int ni = 0; ni < 4; ++ni) {
        int col = wc + ni * 16 + lm;
        float bv = bias[col0 + col];
#pragma unroll
        for (int r = 0; r < 4; ++r)
          smem[(wr + mi * 16 + lk * 4 + r) * 136 + col] = f2bf(acc[mi][ni][r] + bv);
      }
    __syncthreads();
    const int rr = t >> 1, seg = t & 1;
    u16* dst = (u16*)Cp + (size_t)(row0 + rr) * Nn + col0 + seg * 64;
    const u16* src = smem + rr * 136 + seg * 64;
#pragma unroll
    for (int i = 0; i < 8; ++i)
      *(int4*)(dst + i * 8) = *(const int4*)(src + i * 8);
  } else {
    float* smf = (float*)smem;
    for (int half = 0; half < 2; ++half) {
      __syncthreads();
      if ((w >> 1) == half) {
#pragma unroll
        for (int mi = 0; mi < 4; ++mi)
#pragma unroll
          for (int ni = 0; ni < 4; ++ni) {
            int col = wc + ni * 16 + lm;
            float bv = bias[col0 + col];
#pragma unroll
            for (int r = 0; r < 4; ++r)
              smf[(mi * 16 + lk * 4 + r) * 132 + col] = acc[mi][ni][r] + bv;
          }
      }
      __syncthreads();
      const int rr = t >> 2, seg = t & 3;
      float* dst = (float*)Cp + (size_t)(row0 + half * 64 + rr) * Nn + col0 + seg * 32;
      const float* src = smf + rr * 132 + seg * 32;
#pragma unroll
      for (int i = 0; i < 8; ++i)
        *(float4*)(dst + i * 4) = *(const float4*)(src + i * 4);
    }
  }
}

// ---------------- fused window attention: 4 waves/block, wave=(window,head) ----------------
// Per-wave private LDS slices; waves never synchronize (no __syncthreads).
__global__ __launch_bounds__(256) void k_attn(const u16* __restrict__ qkv,
                                              const float* __restrict__ biasM,
                                              const float* __restrict__ maskT,
                                              u16* __restrict__ aout) {
  __shared__ u16 sm[4 * 6528];            // per wave: sP 64x68 + sV 32x68 (u16)
  const int bid = blockIdx.x;
  const int wdx = bid >> 2;               // window 0..2047
  const int wv  = threadIdx.x >> 6;
  const int h   = ((bid & 3) << 2) + wv;  // head 0..15
  const int mw  = wdx & 63;
  const int l   = threadIdx.x & 63;
  const int lm  = l & 15, lk = l >> 4;
  const size_t tb = (size_t)wdx * NTOK;
  const u16* base = qkv + tb * 1536;
  u16* sP = sm + wv * 6528;
  u16* sV = sP + 4352;                    // 64*68

  const int4  iz = make_int4(0, 0, 0, 0);
  const f32x4 fz = {0.f, 0.f, 0.f, 0.f};

  // stage V transposed: sV[d][n] = V[n][d]
  {
    const int n = l;
    const u16* vp = base + (size_t)n * 1536 + 1024 + h * 32;
#pragma unroll
    for (int d0 = 0; d0 < 4; d0++) {
      int4 vv = (n < NTOK) ? *(const int4*)(vp + d0 * 8) : iz;
      const u16* u = (const u16*)&vv;
#pragma unroll
      for (int j = 0; j < 8; j++) sV[(d0 * 8 + j) * 68 + n] = u[j];
    }
  }

  bf16x8 qf[4], kf[4];
#pragma unroll
  for (int i = 0; i < 4; i++) {
    int m = i * 16 + lm;
    int4 qi = (m < NTOK) ? *(const int4*)(base + (size_t)m * 1536 +       h * 32 + lk * 8) : iz;
    int4 ki = (m < NTOK) ? *(const int4*)(base + (size_t)m * 1536 + 512 + h * 32 + lk * 8) : iz;
    qf[i] = __builtin_bit_cast(bf16x8, qi);
    kf[i] = __builtin_bit_cast(bf16x8, ki);
  }

  f32x4 s[4][4];
#pragma unroll
  for (int mi = 0; mi < 4; mi++)
#pragma unroll
    for (int ni = 0; ni < 4; ni++)
      s[mi][ni] = __builtin_amdgcn_mfma_f32_16x16x32_bf16(qf[mi], kf[ni], fz, 0, 0, 0);

  const float* bM = biasM + (h << 12);
  const float* mT = maskT + (mw << 12);
  float rinv[4][4];

#pragma unroll
  for (int mi = 0; mi < 4; mi++) {
    float rmax[4] = {-3e38f, -3e38f, -3e38f, -3e38f};
#pragma unroll
    for (int ni = 0; ni < 4; ni++) {
#pragma unroll
      for (int r = 0; r < 4; r++) {
        int off = mi * 1024 + lk * 256 + r * 64 + ni * 16 + lm;
        float v = s[mi][ni][r] + bM[off] + mT[off];   // Q pre-scaled in weights
        s[mi][ni][r] = v;
        rmax[r] = fmaxf(rmax[r], v);
      }
    }
#pragma unroll
    for (int r = 0; r < 4; r++) {
      float m = rmax[r];
#pragma unroll
      for (int d = 1; d < 16; d <<= 1) m = fmaxf(m, __shfl_xor(m, d, 64));
      rmax[r] = m;
    }
    float rsum[4] = {0.f, 0.f, 0.f, 0.f};
#pragma unroll
    for (int ni = 0; ni < 4; ni++) {
#pragma unroll
      for (int r = 0; r < 4; r++) {
        float p = __expf(s[mi][ni][r] - rmax[r]);
        s[mi][ni][r] = p;
        rsum[r] += p;
      }
    }
#pragma unroll
    for (int r = 0; r < 4; r++) {
      float sm2 = rsum[r];
#pragma unroll
      for (int d = 1; d < 16; d <<= 1) sm2 += __shfl_xor(sm2, d, 64);
      rinv[mi][r] = 1.f / sm2;
    }
#pragma unroll
    for (int ni = 0; ni < 4; ni++)
#pragma unroll
      for (int r = 0; r < 4; r++)
        sP[(mi * 16 + lk * 4 + r) * 68 + ni * 16 + lm] = f2bf(s[mi][ni][r]);
  }

  // O = P @ V (per-wave LDS; compiler orders DS write->read on same arrays)
  f32x4 o[4][2];
#pragma unroll
  for (int mi = 0; mi < 4; mi++) { o[mi][0] = fz; o[mi][1] = fz; }
#pragma unroll
  for (int kt = 0; kt < 2; kt++) {
    bf16x8 vb[2];
#pragma unroll
    for (int df = 0; df < 2; df++)
      vb[df] = *(const bf16x8*)(sV + (df * 16 + lm) * 68 + kt * 32 + lk * 8);
#pragma unroll
    for (int mi = 0; mi < 4; mi++) {
      bf16x8 pa = *(const bf16x8*)(sP + (mi * 16 + lm) * 68 + kt * 32 + lk * 8);
      o[mi][0] = __builtin_amdgcn_mfma_f32_16x16x32_bf16(pa, vb[0], o[mi][0], 0, 0, 0);
      o[mi][1] = __builtin_amdgcn_mfma_f32_16x16x32_bf16(pa, vb[1], o[mi][1], 0, 0, 0);
    }
  }

#pragma unroll
  for (int mi = 0; mi < 4; mi++) {
#pragma unroll
    for (int r = 0; r < 4; r++) {
      int row = mi * 16 + lk * 4 + r;
      if (row < NTOK) {
        float inv = rinv[mi][r];
        size_t ob = (tb + row) * CH + h * 32;
        aout[ob + lm]      = f2bf(o[mi][0][r] * inv);
        aout[ob + 16 + lm] = f2bf(o[mi][1][r] * inv);
      }
    }
  }
}

extern "C" void kernel_launch(void* const* d_in, const int* in_sizes, int n_in,
                              void* d_out, int out_size, void* d_ws, size_t ws_size,
                              hipStream_t stream) {
  const float* x      = (const float*)d_in[0];
  const float* qkv_b  = (const float*)d_in[2];
  const float* proj_b = (const float*)d_in[4];
  const float* btab   = (const float*)d_in[5];

  char* ws   = (char*)d_ws;
  u16* Wt    = (u16*)ws;                                  // 1,572,864 B
  u16* Pt    = (u16*)(ws + 1572864);                      //   524,288 B
  u16* qkv   = (u16*)(ws + 2097152);                      // 308,281,344 B
  u16* aout  = (u16*)(ws + 2097152 + 308281344ull);       // 102,760,448 B (aliased xb)
  u16* xb    = aout;                                      // dead once attn writes aout
  float* biasM = (float*)(ws + 2097152 + 308281344ull + 102760448ull);  // 262,144 B
  float* maskT = biasM + 65536;                           // 1,048,576 B
  float* bias2 = maskT + 262144;                          //     6,144 B
  float* out = (float*)d_out;

  k_wprep<<<4096, 256, 0, stream>>>((const float*)d_in[1], (const float*)d_in[3],
                                    qkv_b, Wt, Pt, bias2);
  k_xcast<<<25088, 256, 0, stream>>>(x, xb);
  k_tabs<<<1280, 256, 0, stream>>>(btab, biasM, maskT);
  k_gemm<0><<<784 * 12, 256, 0, stream>>>(xb, Wt, bias2, (void*)qkv, 100352, 1536, 512, 12);
  k_attn<<<2048 * 4, 256, 0, stream>>>(qkv, biasM, maskT, aout);
  k_gemm<1><<<784 * 4, 256, 0, stream>>>(aout, Pt, proj_b, (void*)out, 100352, 512, 512, 4);
}

// Round 4
// 733.182 us; speedup vs baseline: 1.7612x; 1.1263x over previous
//
#include <hip/hip_runtime.h>
#include <hip/hip_bf16.h>
#include <stdint.h>

// WindowAttention (Swin, shifted): x[2048,49,512] f32 -> out[2048,49,512] f32
// Pipeline:
//   k_wprep: cast+transpose weights to bf16 [N][K]; q-cols pre-scaled by 32^-0.5; bias2
//   k_xcast: x f32 -> bf16 (into aout region, dead until attn writes it)
//   k_tabs : bias[h][64][64], mask[mw][64][64] f32 tables (pad rows/cols = -1e30)
//   k_gemm<0>: qkv = xb @ Wt^T + bias2     (bf16 out, 158 GF)
//   k_attn : 4-wave blocks, wave=(window,head): softmax(QK^T + bias + mask) @ V
//   k_gemm<1>: out = aout @ Pt^T + proj_b  (f32 out, 53 GF)
// GEMM LDS tiles use T2 XOR-swizzle (chunk ^= row&7), applied on BOTH sides:
// pre-swizzled global source (gload_lds writes linearly) + swizzled ds_read.

#define HEADS 16
#define NTOK  49
#define CH    512

typedef float  f32x4  __attribute__((ext_vector_type(4)));
typedef __bf16 bf16x8 __attribute__((ext_vector_type(8)));
typedef unsigned short u16;
typedef unsigned int   u32;

__device__ __forceinline__ u16 f2bf(float f) {
  return __builtin_bit_cast(u16, (__bf16)f);   // native v_cvt, RNE
}

__device__ __forceinline__ void gload16(const u16* g, u16* l) {
  __builtin_amdgcn_global_load_lds(
      (const __attribute__((address_space(1))) u32*)g,
      (__attribute__((address_space(3))) u32*)l, 16, 0, 0);
}

// ---------------- weight prep (+ q-scale folding) ----------------
__global__ __launch_bounds__(256) void k_wprep(const float* __restrict__ qkv_w,
                                               const float* __restrict__ proj_w,
                                               const float* __restrict__ qkv_b,
                                               u16* __restrict__ Wt, u16* __restrict__ Pt,
                                               float* __restrict__ bias2) {
  const float sc = 0.17677669529663687f;       // 32^-0.5
  int tid = blockIdx.x * 256 + threadIdx.x;
  const int T1 = 1536 * 512;
  if (tid < 1536) bias2[tid] = qkv_b[tid] * (tid < 512 ? sc : 1.f);
  if (tid < T1) {
    int n = tid >> 9, k = tid & 511;
    float v = qkv_w[k * 1536 + n];
    if (n < 512) v *= sc;
    Wt[tid] = f2bf(v);
  } else {
    int t2 = tid - T1;
    int n = t2 >> 9, k = t2 & 511;
    Pt[t2] = f2bf(proj_w[k * 512 + n]);
  }
}

// ---------------- x cast: f32 -> bf16, 8 elems/thread ----------------
__global__ __launch_bounds__(256) void k_xcast(const float* __restrict__ x,
                                               u16* __restrict__ xb) {
  int tid = blockIdx.x * 256 + threadIdx.x;
  const float4* xv = (const float4*)x;
  float4 a = xv[tid * 2], b = xv[tid * 2 + 1];
  u16 o[8] = {f2bf(a.x), f2bf(a.y), f2bf(a.z), f2bf(a.w),
              f2bf(b.x), f2bf(b.y), f2bf(b.z), f2bf(b.w)};
  ((int4*)xb)[tid] = *(const int4*)o;
}

// ---------------- bias/mask tables ----------------
__global__ __launch_bounds__(256) void k_tabs(const float* __restrict__ bias_table,
                                              float* __restrict__ biasM,
                                              float* __restrict__ maskT) {
  int tid = blockIdx.x * 256 + threadIdx.x;
  if (tid < 16 * 4096) {
    int h = tid >> 12, rc = tid & 4095, r = rc >> 6, c = rc & 63;
    float v = -1e30f;
    if (r < NTOK && c < NTOK) {
      int ih = r / 7, iw = r - ih * 7, jh = c / 7, jw = c - jh * 7;
      v = bias_table[((ih - jh + 6) * 13 + (iw - jw + 6)) * HEADS + h];
    }
    biasM[tid] = v;
  } else {
    int t2 = tid - 65536;
    int mw = t2 >> 12, rc = t2 & 4095, r = rc >> 6, c = rc & 63;
    float v = 0.f;
    if (r < NTOK && c < NTOK) {
      int mwR = (mw >> 3) * 7, mwC = (mw & 7) * 7;
      int ih = r / 7, iw = r - ih * 7, jh = c / 7, jw = c - jh * 7;
      int gih = mwR + ih, giw = mwC + iw, gjh = mwR + jh, gjw = mwC + jw;
      int ri = (gih < 49 ? 0 : (gih < 53 ? 1 : 2)) * 3 + (giw < 49 ? 0 : (giw < 53 ? 1 : 2));
      int rj = (gjh < 49 ? 0 : (gjh < 53 ? 1 : 2)) * 3 + (gjw < 49 ? 0 : (gjw < 53 ? 1 : 2));
      v = (ri != rj) ? -100.f : 0.f;
    }
    maskT[t2] = v;
  }
}

// ---------------- GEMM: C[M][Nn] = A[M][K] @ Bt[Nn][K]^T + bias ----------------
// 128x128 tile, 4 waves (2x2 of 64x64), BK=64, global_load_lds(16B) staging,
// T2 XOR-swizzled LDS (conflict-free ds_read_b128), coalesced LDS epilogue.
template<int OUT_F32>
__global__ __launch_bounds__(256) void k_gemm(const u16* __restrict__ A,
                                              const u16* __restrict__ Bt,
                                              const float* __restrict__ bias,
                                              void* __restrict__ Cp,
                                              int M, int Nn, int K, int nbn) {
  __shared__ u16 smem[128 * 136];
  u16* sA = smem;
  u16* sB = smem + 8192;
  const int t   = threadIdx.x;
  const int bid = blockIdx.x;
  const int cb  = bid % nbn, rb = bid / nbn;
  const int row0 = rb << 7, col0 = cb << 7;
  const int lane = t & 63, w = t >> 6;
  const int wr = (w >> 1) << 6, wc = (w & 1) << 6;
  const int lm = lane & 15, lk = lane >> 4;

  const f32x4 fz = {0.f, 0.f, 0.f, 0.f};
  f32x4 acc[4][4];
#pragma unroll
  for (int i = 0; i < 4; i++)
#pragma unroll
    for (int j = 0; j < 4; j++) acc[i][j] = fz;

  // staging source-chunk swizzle (loop-invariant): chunk c -> c ^ (row&7)
  int gr[4], gc[4], gdb[4];
#pragma unroll
  for (int i = 0; i < 4; ++i) {
    int q = (i << 8) + t;
    gr[i]  = q >> 3;
    gc[i]  = (((q & 7) ^ (gr[i] & 7)) << 3);
    gdb[i] = ((i << 8) + (t & 192)) << 3;    // wave-uniform dest base (u16)
  }
  // read-side swizzled offsets (loop-invariant)
  int offA[4], offB[4];
#pragma unroll
  for (int i = 0; i < 4; ++i) {
    int rowA = wr + i * 16 + lm;
    offA[i] = rowA * 64 + ((lk ^ (rowA & 7)) << 3);
    int rowB = wc + i * 16 + lm;
    offB[i] = rowB * 64 + ((lk ^ (rowB & 7)) << 3);
  }

  const int nk = K >> 6;
  for (int kt = 0; kt < nk; ++kt) {
    const int kb = kt << 6;
    __syncthreads();
#pragma unroll
    for (int i = 0; i < 4; ++i) {
      gload16(A  + (size_t)(row0 + gr[i]) * K + kb + gc[i], sA + gdb[i]);
      gload16(Bt + (size_t)(col0 + gr[i]) * K + kb + gc[i], sB + gdb[i]);
    }
    __syncthreads();
    bf16x8 a[4][2], b[4][2];
#pragma unroll
    for (int mi = 0; mi < 4; ++mi) {
      a[mi][0] = *(const bf16x8*)(sA + offA[mi]);
      a[mi][1] = *(const bf16x8*)(sA + (offA[mi] ^ 32));
    }
#pragma unroll
    for (int ni = 0; ni < 4; ++ni) {
      b[ni][0] = *(const bf16x8*)(sB + offB[ni]);
      b[ni][1] = *(const bf16x8*)(sB + (offB[ni] ^ 32));
    }
#pragma unroll
    for (int kk = 0; kk < 2; ++kk)
#pragma unroll
      for (int mi = 0; mi < 4; ++mi)
#pragma unroll
        for (int ni = 0; ni < 4; ++ni)
          acc[mi][ni] = __builtin_amdgcn_mfma_f32_16x16x32_bf16(a[mi][kk], b[ni][kk],
                                                                acc[mi][ni], 0, 0, 0);
  }

  if constexpr (!OUT_F32) {
    __syncthreads();
#pragma unroll
    for (int mi = 0; mi < 4; ++mi)
#pragma unroll
      for (int ni = 0; ni < 4; ++ni) {
        int col = wc + ni * 16 + lm;
        float bv = bias[col0 + col];
#pragma unroll
        for (int r = 0; r < 4; ++r)
          smem[(wr + mi * 16 + lk * 4 + r) * 136 + col] = f2bf(acc[mi][ni][r] + bv);
      }
    __syncthreads();
    const int rr = t >> 1, seg = t & 1;
    u16* dst = (u16*)Cp + (size_t)(row0 + rr) * Nn + col0 + seg * 64;
    const u16* src = smem + rr * 136 + seg * 64;
#pragma unroll
    for (int i = 0; i < 8; ++i)
      *(int4*)(dst + i * 8) = *(const int4*)(src + i * 8);
  } else {
    float* smf = (float*)smem;
    for (int half = 0; half < 2; ++half) {
      __syncthreads();
      if ((w >> 1) == half) {
#pragma unroll
        for (int mi = 0; mi < 4; ++mi)
#pragma unroll
          for (int ni = 0; ni < 4; ++ni) {
            int col = wc + ni * 16 + lm;
            float bv = bias[col0 + col];
#pragma unroll
            for (int r = 0; r < 4; ++r)
              smf[(mi * 16 + lk * 4 + r) * 132 + col] = acc[mi][ni][r] + bv;
          }
      }
      __syncthreads();
      const int rr = t >> 2, seg = t & 3;
      float* dst = (float*)Cp + (size_t)(row0 + half * 64 + rr) * Nn + col0 + seg * 32;
      const float* src = smf + rr * 132 + seg * 32;
#pragma unroll
      for (int i = 0; i < 8; ++i)
        *(float4*)(dst + i * 4) = *(const float4*)(src + i * 4);
    }
  }
}

// ---------------- fused window attention: 4 waves/block, wave=(window,head) ----------------
__global__ __launch_bounds__(256) void k_attn(const u16* __restrict__ qkv,
                                              const float* __restrict__ biasM,
                                              const float* __restrict__ maskT,
                                              u16* __restrict__ aout) {
  __shared__ u16 sm[4 * 6528];            // per wave: sP 64x68 + sV 32x68 (u16)
  const int bid = blockIdx.x;
  const int wdx = bid >> 2;               // window 0..2047
  const int wv  = threadIdx.x >> 6;
  const int h   = ((bid & 3) << 2) + wv;  // head 0..15
  const int mw  = wdx & 63;
  const int l   = threadIdx.x & 63;
  const int lm  = l & 15, lk = l >> 4;
  const size_t tb = (size_t)wdx * NTOK;
  const u16* base = qkv + tb * 1536;
  u16* sP = sm + wv * 6528;
  u16* sV = sP + 4352;                    // 64*68

  const int4  iz = make_int4(0, 0, 0, 0);
  const f32x4 fz = {0.f, 0.f, 0.f, 0.f};

  // stage V transposed: sV[d][n] = V[n][d]
  {
    const int n = l;
    const u16* vp = base + (size_t)n * 1536 + 1024 + h * 32;
#pragma unroll
    for (int d0 = 0; d0 < 4; d0++) {
      int4 vv = (n < NTOK) ? *(const int4*)(vp + d0 * 8) : iz;
      const u16* u = (const u16*)&vv;
#pragma unroll
      for (int j = 0; j < 8; j++) sV[(d0 * 8 + j) * 68 + n] = u[j];
    }
  }

  bf16x8 qf[4], kf[4];
#pragma unroll
  for (int i = 0; i < 4; i++) {
    int m = i * 16 + lm;
    int4 qi = (m < NTOK) ? *(const int4*)(base + (size_t)m * 1536 +       h * 32 + lk * 8) : iz;
    int4 ki = (m < NTOK) ? *(const int4*)(base + (size_t)m * 1536 + 512 + h * 32 + lk * 8) : iz;
    qf[i] = __builtin_bit_cast(bf16x8, qi);
    kf[i] = __builtin_bit_cast(bf16x8, ki);
  }

  f32x4 s[4][4];
#pragma unroll
  for (int mi = 0; mi < 4; mi++)
#pragma unroll
    for (int ni = 0; ni < 4; ni++)
      s[mi][ni] = __builtin_amdgcn_mfma_f32_16x16x32_bf16(qf[mi], kf[ni], fz, 0, 0, 0);

  const float* bM = biasM + (h << 12);
  const float* mT = maskT + (mw << 12);
  float rinv[4][4];

#pragma unroll
  for (int mi = 0; mi < 4; mi++) {
    float rmax[4] = {-3e38f, -3e38f, -3e38f, -3e38f};
#pragma unroll
    for (int ni = 0; ni < 4; ni++) {
#pragma unroll
      for (int r = 0; r < 4; r++) {
        int off = mi * 1024 + lk * 256 + r * 64 + ni * 16 + lm;
        float v = s[mi][ni][r] + bM[off] + mT[off];   // Q pre-scaled in weights
        s[mi][ni][r] = v;
        rmax[r] = fmaxf(rmax[r], v);
      }
    }
#pragma unroll
    for (int r = 0; r < 4; r++) {
      float m = rmax[r];
#pragma unroll
      for (int d = 1; d < 16; d <<= 1) m = fmaxf(m, __shfl_xor(m, d, 64));
      rmax[r] = m;
    }
    float rsum[4] = {0.f, 0.f, 0.f, 0.f};
#pragma unroll
    for (int ni = 0; ni < 4; ni++) {
#pragma unroll
      for (int r = 0; r < 4; r++) {
        float p = __expf(s[mi][ni][r] - rmax[r]);
        s[mi][ni][r] = p;
        rsum[r] += p;
      }
    }
#pragma unroll
    for (int r = 0; r < 4; r++) {
      float sm2 = rsum[r];
#pragma unroll
      for (int d = 1; d < 16; d <<= 1) sm2 += __shfl_xor(sm2, d, 64);
      rinv[mi][r] = 1.f / sm2;
    }
#pragma unroll
    for (int ni = 0; ni < 4; ni++)
#pragma unroll
      for (int r = 0; r < 4; r++)
        sP[(mi * 16 + lk * 4 + r) * 68 + ni * 16 + lm] = f2bf(s[mi][ni][r]);
  }

  // O = P @ V (per-wave LDS; compiler orders DS write->read on same arrays)
  f32x4 o[4][2];
#pragma unroll
  for (int mi = 0; mi < 4; mi++) { o[mi][0] = fz; o[mi][1] = fz; }
#pragma unroll
  for (int kt = 0; kt < 2; kt++) {
    bf16x8 vb[2];
#pragma unroll
    for (int df = 0; df < 2; df++)
      vb[df] = *(const bf16x8*)(sV + (df * 16 + lm) * 68 + kt * 32 + lk * 8);
#pragma unroll
    for (int mi = 0; mi < 4; mi++) {
      bf16x8 pa = *(const bf16x8*)(sP + (mi * 16 + lm) * 68 + kt * 32 + lk * 8);
      o[mi][0] = __builtin_amdgcn_mfma_f32_16x16x32_bf16(pa, vb[0], o[mi][0], 0, 0, 0);
      o[mi][1] = __builtin_amdgcn_mfma_f32_16x16x32_bf16(pa, vb[1], o[mi][1], 0, 0, 0);
    }
  }

#pragma unroll
  for (int mi = 0; mi < 4; mi++) {
#pragma unroll
    for (int r = 0; r < 4; r++) {
      int row = mi * 16 + lk * 4 + r;
      if (row < NTOK) {
        float inv = rinv[mi][r];
        size_t ob = (tb + row) * CH + h * 32;
        aout[ob + lm]      = f2bf(o[mi][0][r] * inv);
        aout[ob + 16 + lm] = f2bf(o[mi][1][r] * inv);
      }
    }
  }
}

extern "C" void kernel_launch(void* const* d_in, const int* in_sizes, int n_in,
                              void* d_out, int out_size, void* d_ws, size_t ws_size,
                              hipStream_t stream) {
  const float* x      = (const float*)d_in[0];
  const float* qkv_b  = (const float*)d_in[2];
  const float* proj_b = (const float*)d_in[4];
  const float* btab   = (const float*)d_in[5];

  char* ws   = (char*)d_ws;
  u16* Wt    = (u16*)ws;                                  // 1,572,864 B
  u16* Pt    = (u16*)(ws + 1572864);                      //   524,288 B
  u16* qkv   = (u16*)(ws + 2097152);                      // 308,281,344 B
  u16* aout  = (u16*)(ws + 2097152 + 308281344ull);       // 102,760,448 B (aliased xb)
  u16* xb    = aout;                                      // dead once attn writes aout
  float* biasM = (float*)(ws + 2097152 + 308281344ull + 102760448ull);  // 262,144 B
  float* maskT = biasM + 65536;                           // 1,048,576 B
  float* bias2 = maskT + 262144;                          //     6,144 B
  float* out = (float*)d_out;

  k_wprep<<<4096, 256, 0, stream>>>((const float*)d_in[1], (const float*)d_in[3],
                                    qkv_b, Wt, Pt, bias2);
  k_xcast<<<25088, 256, 0, stream>>>(x, xb);
  k_tabs<<<1280, 256, 0, stream>>>(btab, biasM, maskT);
  k_gemm<0><<<784 * 12, 256, 0, stream>>>(xb, Wt, bias2, (void*)qkv, 100352, 1536, 512, 12);
  k_attn<<<2048 * 4, 256, 0, stream>>>(qkv, biasM, maskT, aout);
  k_gemm<1><<<784 * 4, 256, 0, stream>>>(aout, Pt, proj_b, (void*)out, 100352, 512, 512, 4);
}